// Round 1
// baseline (15566.127 us; speedup 1.0000x reference)
//
#include <hip/hip_runtime.h>
#include <hip/hip_fp16.h>
#include <stdint.h>

typedef _Float16 f16;
typedef _Float16 f16x8 __attribute__((ext_vector_type(8)));
typedef _Float16 f16x4 __attribute__((ext_vector_type(4)));
typedef float f32x4 __attribute__((ext_vector_type(4)));

#define TSTEPS 512
#define NB 256        // grid blocks = CUs (1 block/CU forced by LDS usage)
#define NT 512        // 8 waves per block
#define COLPAD 2056   // 2048 + 8 f16 pad -> breaks power-of-2 LDS stride conflicts

__device__ __forceinline__ float sigm(float v) { return 1.0f / (1.0f + __expf(-v)); }

// Sense-reversal grid barrier in d_ws. All 256 blocks are co-resident
// (148.6KB LDS -> 1 block/CU, 256 blocks on 256 CUs), so spinning is safe.
__device__ __forceinline__ void grid_barrier(unsigned* cnt, unsigned* gen, unsigned& myGen) {
  __syncthreads();
  if (threadIdx.x == 0) {
    __threadfence();  // make this block's h-writes visible device-wide
    const unsigned g = myGen;
    const unsigned a = __hip_atomic_fetch_add(cnt, 1u, __ATOMIC_ACQ_REL, __HIP_MEMORY_SCOPE_AGENT);
    if (a == NB - 1) {
      __hip_atomic_store(cnt, 0u, __ATOMIC_RELAXED, __HIP_MEMORY_SCOPE_AGENT);
      __hip_atomic_store(gen, g + 1u, __ATOMIC_RELEASE, __HIP_MEMORY_SCOPE_AGENT);
    } else {
      while (__hip_atomic_load(gen, __ATOMIC_ACQUIRE, __HIP_MEMORY_SCOPE_AGENT) < g + 1u) {
        __builtin_amdgcn_s_sleep(1);
      }
    }
    myGen = g + 1u;
  }
  __syncthreads();
}

// Persistent wavefront-pipelined 2-layer subLSTM.
// Block bid: layer = bid>>7 (128 blocks each), owns hidden units [8n, 8n+8), n = bid&127.
// Per interval s: layer-1 computes step t=s, layer-2 computes step t=s-1.
// Step GEMM per block: C[32b x 32col] = A[32 x 2048] * B[2048 x 32], fp16 MFMA 16x16x32.
// A = [x_t | h1] (layer1) or [out1_{t} | h2] (layer2). B = packed [w_ih ; w_hh] slice,
// persistent in LDS. col = type*8 + jj, gate = type*1024 + 8n + jj (types: i,o,z,f).
template<int USE_X16>
__global__ __launch_bounds__(NT)
void sublstm_persistent(const float* __restrict__ x,
                        const float* __restrict__ wih0, const float* __restrict__ whh0,
                        const float* __restrict__ b0,
                        const float* __restrict__ wih1, const float* __restrict__ whh1,
                        const float* __restrict__ b1,
                        const f16* __restrict__ x16,
                        f16* __restrict__ h1buf, f16* __restrict__ h2buf,
                        unsigned* __restrict__ bar,
                        float* __restrict__ out)
{
  __shared__ f16  ldsB[32 * COLPAD];     // 131,584 B  weight slice, persistent
  __shared__ float red[8][16][32];       //  16,384 B  per-wave partial C
  __shared__ float gatesS[32][32];       //   4,096 B  sigmoided gates
  __shared__ float biasS[32];            //     128 B

  const int bid   = blockIdx.x;
  const int layer = bid >> 7;
  const int n     = bid & 127;
  const int tid   = threadIdx.x;
  const int lane  = tid & 63;
  const int wave  = tid >> 6;
  const int m     = wave & 1;    // M-row tile (batch 0-15 / 16-31)
  const int kq    = wave >> 1;   // K quarter: [kq*512, kq*512+512)

  const float* wih = layer ? wih1 : wih0;
  const float* whh = layer ? whh1 : whh0;
  const float* bb  = layer ? b1   : b0;

  // One-time gather: fp32 weights -> fp16 LDS in B-fragment-friendly [col][k] layout.
  for (int idx = tid; idx < 32 * 2048; idx += NT) {
    const int col = idx >> 11, k = idx & 2047;
    const int gate = ((col >> 3) << 10) + (n << 3) + (col & 7);
    const float wv = (k < 1024) ? wih[(size_t)gate * 1024 + k]
                                : whh[(size_t)gate * 1024 + (k - 1024)];
    ldsB[col * COLPAD + k] = (f16)wv;
  }
  if (tid < 32) biasS[tid] = bb[((tid >> 3) << 10) + (n << 3) + (tid & 7)];
  __syncthreads();

  float c = 0.0f;          // cell state: thread tid<256 owns (b=tid>>3, jj=tid&7)
  unsigned myGen = 0;

  const int brow = m * 16 + (lane & 15);   // batch row this lane loads for A
  const int ko   = (lane >> 4) * 8;        // k sub-offset within 32-wide K step
  const int colb = lane & 15;

  for (int s = 0; s <= TSTEPS; ++s) {
    const int p_in  = s & 1;
    const int p_out = (s + 1) & 1;
    const bool active = (layer == 0) ? (s < TSTEPS) : (s >= 1);
    const int t = (layer == 0) ? s : (s - 1);

    if (active) {
      const f16* A0 = (layer == 0) ? (x16 + (size_t)t * (32 * 1024))
                                   : (h1buf + (size_t)p_in * (32 * 1024));
      const f16* A1 = ((layer == 0) ? h1buf : h2buf) + (size_t)p_in * (32 * 1024);

      f32x4 acc0a = {0,0,0,0}, acc0b = {0,0,0,0}, acc1a = {0,0,0,0}, acc1b = {0,0,0,0};
      #pragma unroll
      for (int ks = 0; ks < 16; ++ks) {
        const int kk = kq * 512 + ks * 32 + ko;    // global K index, 0..2047
        f16x8 afrag;
        if (USE_X16 == 0 && layer == 0 && kq < 2) {
          const float* xp = x + ((size_t)t * 32 + brow) * 1024 + kk;
          const float4 v0 = *(const float4*)xp;
          const float4 v1 = *(const float4*)(xp + 4);
          afrag = (f16x8){(f16)v0.x,(f16)v0.y,(f16)v0.z,(f16)v0.w,
                          (f16)v1.x,(f16)v1.y,(f16)v1.z,(f16)v1.w};
        } else {
          const f16* ap = (kk < 1024) ? (A0 + (size_t)brow * 1024 + kk)
                                      : (A1 + (size_t)brow * 1024 + (kk - 1024));
          afrag = *(const f16x8*)ap;
        }
        const f16x8 bf0 = *(const f16x8*)&ldsB[colb * COLPAD + kk];
        const f16x8 bf1 = *(const f16x8*)&ldsB[(colb + 16) * COLPAD + kk];
        if (ks & 1) {
          acc0b = __builtin_amdgcn_mfma_f32_16x16x32_f16(afrag, bf0, acc0b, 0, 0, 0);
          acc1b = __builtin_amdgcn_mfma_f32_16x16x32_f16(afrag, bf1, acc1b, 0, 0, 0);
        } else {
          acc0a = __builtin_amdgcn_mfma_f32_16x16x32_f16(afrag, bf0, acc0a, 0, 0, 0);
          acc1a = __builtin_amdgcn_mfma_f32_16x16x32_f16(afrag, bf1, acc1a, 0, 0, 0);
        }
      }
      const f32x4 acc0 = acc0a + acc0b;
      const f32x4 acc1 = acc1a + acc1b;
      // C frag layout (16x16x32): col = lane&15, row = (lane>>4)*4 + reg
      const int r0 = (lane >> 4) * 4;
      #pragma unroll
      for (int r = 0; r < 4; ++r) {
        red[wave][r0 + r][colb]      = acc0[r];
        red[wave][r0 + r][colb + 16] = acc1[r];
      }
    }
    __syncthreads();

    if (active) {
      // reduce 4 K-quarter partials, add bias, sigmoid
      #pragma unroll
      for (int idx = tid; idx < 1024; idx += NT) {
        const int b = idx >> 5, col = idx & 31;
        const int mm = b >> 4, r16 = b & 15;
        const float tot = biasS[col]
            + red[0 + mm][r16][col] + red[2 + mm][r16][col]
            + red[4 + mm][r16][col] + red[6 + mm][r16][col];
        gatesS[b][col] = sigm(tot);
      }
    }
    __syncthreads();

    if (active && tid < 256) {
      const int b = tid >> 3, jj = tid & 7;
      const float ig = gatesS[b][jj];
      const float og = gatesS[b][8 + jj];
      const float zg = gatesS[b][16 + jj];
      const float fg = gatesS[b][24 + jj];
      c = c * fg + zg - ig;
      const float h = sigm(c) - og;
      const int j = (n << 3) + jj;
      f16* hb = ((layer == 0) ? h1buf : h2buf) + (size_t)p_out * (32 * 1024);
      hb[b * 1024 + j] = (f16)h;
      if (layer == 1) out[((size_t)t * 32 + b) * 1024 + j] = h;
    }

    grid_barrier(bar, bar + 1, myGen);
  }
}

__global__ void cvt_x_kernel(const float4* __restrict__ in, f16x4* __restrict__ outv, int n4) {
  int i = blockIdx.x * blockDim.x + threadIdx.x;
  const int stride = gridDim.x * blockDim.x;
  for (; i < n4; i += stride) {
    const float4 v = in[i];
    outv[i] = (f16x4){(f16)v.x, (f16)v.y, (f16)v.z, (f16)v.w};
  }
}

extern "C" void kernel_launch(void* const* d_in, const int* in_sizes, int n_in,
                              void* d_out, int out_size, void* d_ws, size_t ws_size,
                              hipStream_t stream) {
  const float* x    = (const float*)d_in[0];
  const float* wih0 = (const float*)d_in[1];
  const float* whh0 = (const float*)d_in[2];
  const float* b0   = (const float*)d_in[3];
  const float* wih1 = (const float*)d_in[4];
  const float* whh1 = (const float*)d_in[5];
  const float* b1   = (const float*)d_in[6];
  float* out = (float*)d_out;

  const size_t X16B   = (size_t)512 * 32 * 1024 * 2;  // 33,554,432 B fp16 copy of x
  const size_t HBUFB  = 2 * 32 * 1024 * 2;            // 131,072 B per double-buffered h
  const size_t STATEB = 2 * HBUFB + 256;              // h1 + h2 + barrier counters

  char* ws = (char*)d_ws;
  const bool use_x16 = ws_size >= X16B + STATEB;
  const size_t soff = use_x16 ? X16B : 0;
  f16* x16        = (f16*)ws;
  f16* h1buf      = (f16*)(ws + soff);
  f16* h2buf      = (f16*)(ws + soff + HBUFB);
  unsigned* bar   = (unsigned*)(ws + soff + 2 * HBUFB);

  // zero h state + barrier counters (ws is poisoned, and graph replays reuse it)
  hipMemsetAsync(ws + soff, 0, STATEB, stream);

  if (use_x16) {
    const int n4 = 512 * 32 * 1024 / 4;
    cvt_x_kernel<<<2048, 256, 0, stream>>>((const float4*)x, (f16x4*)x16, n4);
    sublstm_persistent<1><<<NB, NT, 0, stream>>>(x, wih0, whh0, b0, wih1, whh1, b1,
                                                 x16, h1buf, h2buf, bar, out);
  } else {
    sublstm_persistent<0><<<NB, NT, 0, stream>>>(x, wih0, whh0, b0, wih1, whh1, b1,
                                                 x16, h1buf, h2buf, bar, out);
  }
}

// Round 2
// 4794.406 us; speedup vs baseline: 3.2467x; 3.2467x over previous
//
#include <hip/hip_runtime.h>
#include <hip/hip_fp16.h>
#include <stdint.h>

typedef _Float16 f16;
typedef _Float16 f16x8 __attribute__((ext_vector_type(8)));
typedef _Float16 f16x4 __attribute__((ext_vector_type(4)));
typedef float f32x4 __attribute__((ext_vector_type(4)));

#define TSTEPS 512
#define NB 256        // grid blocks = CUs (1 block/CU forced by LDS usage)
#define NT 512        // 8 waves per block

__device__ __forceinline__ float sigm(float v) { return 1.0f / (1.0f + __expf(-v)); }

// Coherent (L2-bypassing, lands at memory-side L3 = device coherence point)
// accesses for cross-XCD h exchange. No cache-wide inv/wb anywhere.
__device__ __forceinline__ void ld_coh(f16x8& d, const f16* p) {
  asm volatile("global_load_dwordx4 %0, %1, off sc0 sc1" : "=v"(d) : "v"(p));
}
__device__ __forceinline__ void ld_plain(f16x8& d, const f16* p) {
  asm volatile("global_load_dwordx4 %0, %1, off" : "=v"(d) : "v"(p));
}
__device__ __forceinline__ void st_coh_f16(f16* p, f16 v) {
  asm volatile("global_store_short %0, %1, off sc0 sc1" :: "v"(p), "v"(v) : "memory");
}

// Pure-relaxed sense barrier: monotonic count (no reset -> no reset/gen race).
// h-stores are write-through (sc1) and drained via vmcnt(0) BEFORE the
// fetch_add, so a spinner that observes gen==target also observes all h data
// at the coherence point (real-time ordering, no acquire/release cache ops).
__device__ __forceinline__ void grid_barrier(unsigned* cnt, unsigned* gen, unsigned& myGen) {
  asm volatile("s_waitcnt vmcnt(0)" ::: "memory");  // drain asm sc1 stores (all threads)
  __syncthreads();
  if (threadIdx.x == 0) {
    const unsigned target = myGen + 1u;
    const unsigned a = __hip_atomic_fetch_add(cnt, 1u, __ATOMIC_RELAXED, __HIP_MEMORY_SCOPE_AGENT);
    if (a == (unsigned)NB * target - 1u) {
      __hip_atomic_store(gen, target, __ATOMIC_RELAXED, __HIP_MEMORY_SCOPE_AGENT);
    } else {
      while (__hip_atomic_load(gen, __ATOMIC_RELAXED, __HIP_MEMORY_SCOPE_AGENT) < target) {
        __builtin_amdgcn_s_sleep(2);
      }
    }
    myGen = target;
  }
  __syncthreads();
}

// Persistent wavefront-pipelined 2-layer subLSTM.
// Block bid: layer = bid>>7, owns hidden units [8n, 8n+8), n = bid&127.
// Interval s: layer-1 computes t=s, layer-2 computes t=s-1.
// Step GEMM per block: C[32b x 32col] = A[32 x 2048] * B[2048 x 32], fp16 MFMA.
// B slice persistent in LDS, XOR-swizzled (byte ^= (col&7)<<4) -> conflict-free
// ds_read_b128 (row stride 4096 B would otherwise be a full bank collision).
template<int USE_X16>
__global__ __launch_bounds__(NT, 2)
void sublstm_persistent(const float* __restrict__ x,
                        const float* __restrict__ wih0, const float* __restrict__ whh0,
                        const float* __restrict__ b0,
                        const float* __restrict__ wih1, const float* __restrict__ whh1,
                        const float* __restrict__ b1,
                        const f16* __restrict__ x16,
                        f16* __restrict__ h1buf, f16* __restrict__ h2buf,
                        unsigned* __restrict__ bar,
                        float* __restrict__ out)
{
  __shared__ f16  ldsB[32 * 2048];       // 131,072 B  weight slice, persistent, swizzled
  __shared__ float red[8][16][32];       //  16,384 B  per-wave partial C
  __shared__ float gatesS[32][32];       //   4,096 B  sigmoided gates
  __shared__ float biasS[32];            //     128 B

  const int bid   = blockIdx.x;
  const int layer = bid >> 7;
  const int n     = bid & 127;
  const int tid   = threadIdx.x;
  const int lane  = tid & 63;
  const int wave  = tid >> 6;
  const int m     = wave & 1;    // M-row tile (batch 0-15 / 16-31)
  const int kq    = wave >> 1;   // K quarter: [kq*512, kq*512+512)

  const float* wih = layer ? wih1 : wih0;
  const float* whh = layer ? whh1 : whh0;
  const float* bb  = layer ? b1   : b0;

  // One-time gather: fp32 weights -> fp16 LDS, [col][k] layout, XOR-swizzled.
  for (int idx = tid; idx < 32 * 2048; idx += NT) {
    const int col = idx >> 11, k = idx & 2047;
    const int gate = ((col >> 3) << 10) + (n << 3) + (col & 7);
    const float wv = (k < 1024) ? wih[(size_t)gate * 1024 + k]
                                : whh[(size_t)gate * 1024 + (k - 1024)];
    const unsigned byte = ((unsigned)col << 12) + ((unsigned)k << 1);
    *(f16*)((char*)ldsB + (byte ^ (unsigned)((col & 7) << 4))) = (f16)wv;
  }
  if (tid < 32) biasS[tid] = bb[((tid >> 3) << 10) + (n << 3) + (tid & 7)];
  __syncthreads();

  float c = 0.0f;          // cell state: thread tid<256 owns (b=tid>>3, jj=tid&7)
  unsigned myGen = 0;

  const int brow = m * 16 + (lane & 15);   // batch row this lane loads for A
  const int ko   = (lane >> 4) * 8;        // k sub-offset within 32-wide K step
  const int colb = lane & 15;
  const unsigned bswz = (unsigned)((colb & 7) << 4);

  for (int s = 0; s <= TSTEPS; ++s) {
    const int p_in  = s & 1;
    const int p_out = (s + 1) & 1;
    const bool active = (layer == 0) ? (s < TSTEPS) : (s >= 1);
    const int t = (layer == 0) ? s : (s - 1);

    if (active) {
      const f16* h1in = h1buf + (size_t)p_in * (32 * 1024);
      const f16* h2in = h2buf + (size_t)p_in * (32 * 1024);

      // ---- batched A-fragment prefetch: one L3 round-trip per step ----
      f16x8 af[16];
      if (layer == 0 && kq < 2) {
        if (USE_X16) {
          const f16* base = x16 + ((size_t)t * 32 + brow) * 1024 + kq * 512 + ko;
          #pragma unroll
          for (int ks = 0; ks < 16; ++ks) ld_plain(af[ks], base + ks * 32);
        } else {
          const float* base = x + ((size_t)t * 32 + brow) * 1024 + kq * 512 + ko;
          #pragma unroll
          for (int ks = 0; ks < 16; ++ks) {
            const float4 v0 = *(const float4*)(base + ks * 32);
            const float4 v1 = *(const float4*)(base + ks * 32 + 4);
            af[ks] = (f16x8){(f16)v0.x,(f16)v0.y,(f16)v0.z,(f16)v0.w,
                             (f16)v1.x,(f16)v1.y,(f16)v1.z,(f16)v1.w};
          }
        }
      } else {
        const f16* base;
        if (layer == 0)      base = h1in + (size_t)brow * 1024 + (kq - 2) * 512 + ko;
        else if (kq < 2)     base = h1in + (size_t)brow * 1024 + kq * 512 + ko;
        else                 base = h2in + (size_t)brow * 1024 + (kq - 2) * 512 + ko;
        #pragma unroll
        for (int ks = 0; ks < 16; ++ks) ld_coh(af[ks], base + ks * 32);
      }
      asm volatile("s_waitcnt vmcnt(0)" ::: "memory");
      __builtin_amdgcn_sched_barrier(0);

      // ---- MFMA over this wave's K quarter ----
      f32x4 acc0a = {0,0,0,0}, acc0b = {0,0,0,0}, acc1a = {0,0,0,0}, acc1b = {0,0,0,0};
      #pragma unroll
      for (int ks = 0; ks < 16; ++ks) {
        const int kk = kq * 512 + ks * 32 + ko;
        const unsigned byte0 = ((unsigned)colb << 12) + ((unsigned)kk << 1);
        const f16x8 bf0 = *(const f16x8*)((const char*)ldsB + (byte0 ^ bswz));
        const f16x8 bf1 = *(const f16x8*)((const char*)ldsB + ((byte0 + (16u << 12)) ^ bswz));
        if (ks & 1) {
          acc0b = __builtin_amdgcn_mfma_f32_16x16x32_f16(af[ks], bf0, acc0b, 0, 0, 0);
          acc1b = __builtin_amdgcn_mfma_f32_16x16x32_f16(af[ks], bf1, acc1b, 0, 0, 0);
        } else {
          acc0a = __builtin_amdgcn_mfma_f32_16x16x32_f16(af[ks], bf0, acc0a, 0, 0, 0);
          acc1a = __builtin_amdgcn_mfma_f32_16x16x32_f16(af[ks], bf1, acc1a, 0, 0, 0);
        }
      }
      const f32x4 acc0 = acc0a + acc0b;
      const f32x4 acc1 = acc1a + acc1b;
      // C frag layout (16x16x32): col = lane&15, row = (lane>>4)*4 + reg
      const int r0 = (lane >> 4) * 4;
      #pragma unroll
      for (int r = 0; r < 4; ++r) {
        red[wave][r0 + r][colb]      = acc0[r];
        red[wave][r0 + r][colb + 16] = acc1[r];
      }
    }
    __syncthreads();

    if (active) {
      // reduce 4 K-quarter partials, add bias, sigmoid
      #pragma unroll
      for (int idx = tid; idx < 1024; idx += NT) {
        const int b = idx >> 5, col = idx & 31;
        const int mm = b >> 4, r16 = b & 15;
        const float tot = biasS[col]
            + red[0 + mm][r16][col] + red[2 + mm][r16][col]
            + red[4 + mm][r16][col] + red[6 + mm][r16][col];
        gatesS[b][col] = sigm(tot);
      }
    }
    __syncthreads();

    if (active && tid < 256) {
      const int b = tid >> 3, jj = tid & 7;
      const float ig = gatesS[b][jj];
      const float og = gatesS[b][8 + jj];
      const float zg = gatesS[b][16 + jj];
      const float fg = gatesS[b][24 + jj];
      c = c * fg + zg - ig;
      const float h = sigm(c) - og;
      const int j = (n << 3) + jj;
      f16* hb = ((layer == 0) ? h1buf : h2buf) + (size_t)p_out * (32 * 1024);
      st_coh_f16(hb + b * 1024 + j, (f16)h);
      if (layer == 1) out[((size_t)t * 32 + b) * 1024 + j] = h;
    }

    grid_barrier(bar, bar + 32, myGen);
  }
}

__global__ void cvt_x_kernel(const float4* __restrict__ in, f16x4* __restrict__ outv, int n4) {
  int i = blockIdx.x * blockDim.x + threadIdx.x;
  const int stride = gridDim.x * blockDim.x;
  for (; i < n4; i += stride) {
    const float4 v = in[i];
    outv[i] = (f16x4){(f16)v.x, (f16)v.y, (f16)v.z, (f16)v.w};
  }
}

extern "C" void kernel_launch(void* const* d_in, const int* in_sizes, int n_in,
                              void* d_out, int out_size, void* d_ws, size_t ws_size,
                              hipStream_t stream) {
  const float* x    = (const float*)d_in[0];
  const float* wih0 = (const float*)d_in[1];
  const float* whh0 = (const float*)d_in[2];
  const float* b0   = (const float*)d_in[3];
  const float* wih1 = (const float*)d_in[4];
  const float* whh1 = (const float*)d_in[5];
  const float* b1   = (const float*)d_in[6];
  float* out = (float*)d_out;

  const size_t X16B   = (size_t)512 * 32 * 1024 * 2;  // 33,554,432 B fp16 copy of x
  const size_t HBUFB  = 2 * 32 * 1024 * 2;            // 131,072 B per double-buffered h
  const size_t STATEB = 2 * HBUFB + 256;              // h1 + h2 + barrier counters

  char* ws = (char*)d_ws;
  const bool use_x16 = ws_size >= X16B + STATEB;
  const size_t soff = use_x16 ? X16B : 0;
  f16* x16        = (f16*)ws;
  f16* h1buf      = (f16*)(ws + soff);
  f16* h2buf      = (f16*)(ws + soff + HBUFB);
  unsigned* bar   = (unsigned*)(ws + soff + 2 * HBUFB);

  // zero h state + barrier counters (ws is poisoned, and graph replays reuse it)
  hipMemsetAsync(ws + soff, 0, STATEB, stream);

  if (use_x16) {
    const int n4 = 512 * 32 * 1024 / 4;
    cvt_x_kernel<<<2048, 256, 0, stream>>>((const float4*)x, (f16x4*)x16, n4);
    sublstm_persistent<1><<<NB, NT, 0, stream>>>(x, wih0, whh0, b0, wih1, whh1, b1,
                                                 x16, h1buf, h2buf, bar, out);
  } else {
    sublstm_persistent<0><<<NB, NT, 0, stream>>>(x, wih0, whh0, b0, wih1, whh1, b1,
                                                 x16, h1buf, h2buf, bar, out);
  }
}